// Round 1
// baseline (1361.965 us; speedup 1.0000x reference)
//
#include <hip/hip_runtime.h>
#include <hip/hip_bf16.h>

// Problem constants (from reference setup_inputs):
//   B=32, T=2000, H=512, L=200, C=40 (39 phones + blank=39)
// Outputs: log_prob (T,B,C) fp32 flat [0, 2560000) then loss scalar at [2560000].

#define BB 32
#define TT 2000
#define HH 512
#define CC 40
#define LL 200
#define NEGV -1e30f

// ---------------------------------------------------------------------------
// Kernel 1: logits = hidden @ W^T + b, then log_softmax over C, write (T,B,C).
// One thread per (b,t) row. W reads are wave-uniform -> scalar loads (K$).
// ---------------------------------------------------------------------------
__global__ __launch_bounds__(256) void k1_logits_lsm(
    const float* __restrict__ hidden,   // (B,T,H)
    const float* __restrict__ W,        // (C,H)
    const float* __restrict__ bias,     // (C,)
    float* __restrict__ out)            // (T,B,C) region of d_out
{
    const int r = blockIdx.x * blockDim.x + threadIdx.x;   // row = b*T + t
    if (r >= BB * TT) return;

    const float4* __restrict__ h4 = (const float4*)(hidden + (size_t)r * HH);

    float acc[CC];
    #pragma unroll
    for (int c = 0; c < CC; ++c) acc[c] = 0.0f;

    #pragma unroll 2
    for (int k4 = 0; k4 < HH / 4; ++k4) {
        const float4 h = h4[k4];
        #pragma unroll
        for (int c = 0; c < CC; ++c) {
            // uniform address across the wave -> s_load, broadcast via SGPR
            const float4 w = *(const float4*)(W + c * HH + k4 * 4);
            acc[c] += h.x * w.x + h.y * w.y + h.z * w.z + h.w * w.w;
        }
    }

    #pragma unroll
    for (int c = 0; c < CC; ++c) acc[c] += bias[c];

    // log-softmax over CC
    float mx = acc[0];
    #pragma unroll
    for (int c = 1; c < CC; ++c) mx = fmaxf(mx, acc[c]);
    float s = 0.0f;
    #pragma unroll
    for (int c = 0; c < CC; ++c) s += __expf(acc[c] - mx);
    const float lse = mx + __logf(s);

    const int b = r / TT;
    const int t = r - b * TT;
    float4* __restrict__ o4 = (float4*)(out + ((size_t)t * BB + b) * CC);
    #pragma unroll
    for (int c4 = 0; c4 < CC / 4; ++c4) {
        float4 v;
        v.x = acc[4 * c4 + 0] - lse;
        v.y = acc[4 * c4 + 1] - lse;
        v.z = acc[4 * c4 + 2] - lse;
        v.w = acc[4 * c4 + 3] - lse;
        o4[c4] = v;
    }
}

// ---------------------------------------------------------------------------
// Kernel 2: CTC alpha recurrence. One workgroup per batch; thread s = extended
// state s in [0, 2*tl+1). Double-buffered alpha in LDS, 1 barrier per step.
// lp rows prefetched 3 steps ahead into a 4-deep LDS ring.
// Writes loss_b / tl to ws[b].
// ---------------------------------------------------------------------------
__global__ __launch_bounds__(448) void k2_ctc(
    const float* __restrict__ lp,            // (T,B,C)
    const int* __restrict__ targets,         // (B,L)
    const int* __restrict__ input_lengths,   // (B,)
    const int* __restrict__ target_lengths,  // (B,)
    float* __restrict__ ws)                  // (B,) per-batch loss/len
{
    const int b = blockIdx.x;
    const int s = threadIdx.x;
    const int len = input_lengths[b];
    const int tl  = target_lengths[b];
    const int S   = 2 * tl + 1;              // 401 here

    __shared__ float bufA[2 * LL + 2];
    __shared__ float bufB[2 * LL + 2];
    __shared__ float lpbuf[4][CC];

    // Per-thread extended label + skip flag (registers; no LDS needed).
    int  ext_s = CC - 1;                     // blank
    bool skip  = false;
    if (s < S && (s & 1)) {
        ext_s = targets[b * LL + (s >> 1)];
        if (s >= 3) skip = (ext_s != targets[b * LL + ((s - 3) >> 1)]);
        // s==1: a2 path guarded by (s>=2) below, matches reference padding.
    }

    // Preload lp rows t=0..3
    if (s < CC) {
        #pragma unroll
        for (int t = 0; t < 4; ++t)
            lpbuf[t][s] = lp[((size_t)t * BB + b) * CC + s];
    }
    __syncthreads();

    // t = 0 init: alpha0[s] = emit for s in {0,1}, else NEG
    if (s < S) bufA[s] = (s < 2) ? lpbuf[0][ext_s] : NEGV;
    __syncthreads();

    float* A  = bufA;
    float* Bf = bufB;
    for (int t = 1; t < TT; ++t) {
        // prefetch lp[t+3] into ring slot (t+3)&3 (last used at step t-1)
        if (s < CC && t + 3 < TT)
            lpbuf[(t + 3) & 3][s] = lp[((size_t)(t + 3) * BB + b) * CC + s];

        if (s < S) {
            const float a  = A[s];
            const float a1 = (s >= 1) ? A[s - 1] : NEGV;
            const float a2 = (s >= 2 && skip) ? A[s - 2] : NEGV;
            const float m  = fmaxf(a, fmaxf(a1, a2));
            float v = m + __logf(__expf(a - m) + __expf(a1 - m) + __expf(a2 - m))
                        + lpbuf[t & 3][ext_s];
            if (t >= len) v = a;             // freeze past input length
            Bf[s] = v;
        }
        __syncthreads();
        float* tmp = A; A = Bf; Bf = tmp;
    }

    if (s == 0) {
        const float ab = A[2 * tl];
        const float al = A[2 * tl - 1];
        const float m  = fmaxf(ab, al);
        float lb = -(m + __logf(__expf(ab - m) + __expf(al - m)));
        if (lb > 1e29f) lb = 0.0f;           // zero_infinity
        ws[b] = lb / (float)tl;
    }
}

// ---------------------------------------------------------------------------
// Kernel 3: mean over batches -> final loss scalar.
// ---------------------------------------------------------------------------
__global__ void k3_reduce(const float* __restrict__ ws, float* __restrict__ loss_out)
{
    if (threadIdx.x == 0 && blockIdx.x == 0) {
        float sum = 0.0f;
        #pragma unroll
        for (int b = 0; b < BB; ++b) sum += ws[b];
        *loss_out = sum / (float)BB;
    }
}

extern "C" void kernel_launch(void* const* d_in, const int* in_sizes, int n_in,
                              void* d_out, int out_size, void* d_ws, size_t ws_size,
                              hipStream_t stream) {
    const float* hidden = (const float*)d_in[0];   // (B,T,H) fp32
    const float* W      = (const float*)d_in[1];   // (C,H)  fp32
    const float* bias   = (const float*)d_in[2];   // (C,)   fp32
    const int* targets  = (const int*)d_in[3];     // (B,L)
    const int* in_len   = (const int*)d_in[4];     // (B,)
    const int* tg_len   = (const int*)d_in[5];     // (B,)

    float* out      = (float*)d_out;                       // log_prob (T,B,C)
    float* loss_out = out + (size_t)TT * BB * CC;          // scalar at [2560000]
    float* ws       = (float*)d_ws;                        // 32 floats

    k1_logits_lsm<<<dim3((BB * TT) / 256), dim3(256), 0, stream>>>(hidden, W, bias, out);
    k2_ctc<<<dim3(BB), dim3(448), 0, stream>>>(out, targets, in_len, tg_len, ws);
    k3_reduce<<<dim3(1), dim3(64), 0, stream>>>(ws, loss_out);
}

// Round 3
// 651.915 us; speedup vs baseline: 2.0892x; 2.0892x over previous
//
#include <hip/hip_runtime.h>
#include <hip/hip_bf16.h>

// Problem constants (from reference setup_inputs):
//   B=32, T=2000, H=512, L=200, C=40 (39 phones + blank=39)
// Outputs: log_prob (T,B,C) fp32 flat [0, 2560000) then loss scalar at [2560000].

#define BB 32
#define TT 2000
#define HH 512
#define CC 40
#define LL 200

// ---------------------------------------------------------------------------
// Kernel 1: logits = hidden @ W^T + b, then log_softmax over C, write (T,B,C).
// One thread per (b,t) row. W staged through LDS in two 40KB k-chunks;
// W reads are wave-uniform -> LDS broadcast (no bank conflicts).
// ---------------------------------------------------------------------------
__global__ __launch_bounds__(256) void k1_logits_lsm(
    const float* __restrict__ hidden,   // (B,T,H)
    const float* __restrict__ W,        // (C,H)
    const float* __restrict__ bias,     // (C,)
    float* __restrict__ out)            // (T,B,C) region of d_out
{
    __shared__ float Wl[CC * 256];      // one 256-wide k-chunk of W: 40 KB
    float4* Wl4 = (float4*)Wl;

    const int tid = threadIdx.x;
    const int r = blockIdx.x * blockDim.x + tid;   // row = b*T + t
    const float4* __restrict__ h4 = (const float4*)(hidden + (size_t)r * HH);
    const float4* __restrict__ W4g = (const float4*)W;   // 128 float4 per class

    float acc[CC];
    #pragma unroll
    for (int c = 0; c < CC; ++c) acc[c] = 0.0f;

    for (int kc = 0; kc < 2; ++kc) {
        __syncthreads();               // protect previous chunk's readers
        // cooperative stage: 2560 float4, 256 threads -> 10 each, coalesced
        #pragma unroll
        for (int i = 0; i < 10; ++i) {
            const int idx = tid + i * 256;         // float4 index in chunk
            const int c   = idx >> 6;              // 64 float4 per class-chunk
            const int j4  = idx & 63;
            Wl4[idx] = W4g[c * 128 + kc * 64 + j4];
        }
        __syncthreads();

        #pragma unroll 2
        for (int k4 = 0; k4 < 64; ++k4) {
            const float4 h = h4[kc * 64 + k4];
            #pragma unroll
            for (int c = 0; c < CC; ++c) {
                const float4 w = Wl4[c * 64 + k4];   // uniform addr -> broadcast
                acc[c] = fmaf(h.x, w.x, fmaf(h.y, w.y,
                         fmaf(h.z, w.z, fmaf(h.w, w.w, acc[c]))));
            }
        }
    }

    #pragma unroll
    for (int c = 0; c < CC; ++c) acc[c] += bias[c];

    // log-softmax over CC
    float mx = acc[0];
    #pragma unroll
    for (int c = 1; c < CC; ++c) mx = fmaxf(mx, acc[c]);
    float s = 0.0f;
    #pragma unroll
    for (int c = 0; c < CC; ++c) s += __expf(acc[c] - mx);
    const float lse = mx + __logf(s);

    const int b = r / TT;
    const int t = r - b * TT;
    float4* __restrict__ o4 = (float4*)(out + ((size_t)t * BB + b) * CC);
    #pragma unroll
    for (int c4 = 0; c4 < CC / 4; ++c4) {
        float4 v;
        v.x = acc[4 * c4 + 0] - lse;
        v.y = acc[4 * c4 + 1] - lse;
        v.z = acc[4 * c4 + 2] - lse;
        v.w = acc[4 * c4 + 3] - lse;
        o4[c4] = v;
    }
}

// ---------------------------------------------------------------------------
// Kernel 2: CTC alpha recurrence, ONE WAVE per batch. All S=2L+1=401 states
// live in registers (7 per lane, blocked: lane l owns s in [7l, 7l+7)).
// FP64 linear (probability) domain: new[s] = (a[s]+a[s-1]+skip*a[s-2])*p[s].
// Double gives +-709 nats of range vs fp32's +-88 (round-2 failed on fp32
// FTZ underflow: ~2 batches lost all mass -> contrib=0 -> loss error 1.75).
// Wave-max rescale every 8 steps with double logscale accumulator. No LDS
// for alpha, no barriers: neighbor exchange via shfl_up, emission gather via
// ds_bpermute of the fp32 exp(lp) row (lane c holds class c). lp rows
// prefetched 8 steps ahead in a register ring.
// ---------------------------------------------------------------------------
__device__ __forceinline__ float bperm(int byteaddr, float v) {
    return __int_as_float(__builtin_amdgcn_ds_bpermute(byteaddr, __float_as_int(v)));
}

__global__ __launch_bounds__(64) void k2_ctc(
    const float* __restrict__ lp,            // (T,B,C)
    const int* __restrict__ targets,         // (B,L)
    const int* __restrict__ input_lengths,   // (B,)
    const int* __restrict__ target_lengths,  // (B,)
    float* __restrict__ ws)                  // (B,) per-batch loss/len
{
    const int b    = blockIdx.x;
    const int lane = threadIdx.x;
    const int len  = input_lengths[b];
    const int tl   = target_lengths[b];
    const int S    = 2 * tl + 1;             // 401 here

    // Per-state class index (t-invariant) and skip mask, for s = 7*lane + i.
    // Invalid states (s >= S) point at lane 63 which always holds 0.
    int    cad[7];   // bpermute byte address = class*4
    double skf[7];   // 1.0 if s-2 transition allowed
    #pragma unroll
    for (int i = 0; i < 7; ++i) {
        const int s = 7 * lane + i;
        int cls = 63;          // invalid -> gathers 0
        double sk = 0.0;
        if (s < S) {
            if (s & 1) {
                cls = targets[b * LL + (s >> 1)];
                if (s >= 3) {
                    const int prev = targets[b * LL + (s >> 1) - 1];
                    sk = (cls != prev) ? 1.0 : 0.0;
                } else {
                    sk = 1.0;  // s==1: a[s-2] contribution is 0 anyway
                }
            } else {
                cls = CC - 1;  // blank
            }
        }
        cad[i] = cls * 4;
        skf[i] = sk;
    }

    const double lane0m = (lane == 0) ? 0.0 : 1.0;   // zero shfl wrap on lane 0
    const int    lc     = (lane < CC) ? lane : (CC - 1);
    const size_t rowstride = (size_t)BB * CC;
    const float* lprow = lp + (size_t)b * CC + lc;    // + t*rowstride

    // ---- t = 0 init ----
    double a0, a1, a2, a3, a4, a5, a6;
    {
        const float v0 = lprow[0];
        const float e  = (lane < CC) ? __expf(v0) : 0.0f;
        const float e0 = bperm(cad[0], e);
        const float e1 = bperm(cad[1], e);
        a0 = (lane == 0) ? (double)e0 : 0.0;
        a1 = (lane == 0) ? (double)e1 : 0.0;
        a2 = a3 = a4 = a5 = a6 = 0.0;
    }

    // ---- prefetch ring: P[j] holds lp row (t = 1 + j) ----
    float P0 = lprow[1 * rowstride];
    float P1 = lprow[2 * rowstride];
    float P2 = lprow[3 * rowstride];
    float P3 = lprow[4 * rowstride];
    float P4 = lprow[5 * rowstride];
    float P5 = lprow[6 * rowstride];
    float P6 = lprow[7 * rowstride];
    float P7 = lprow[8 * rowstride];

    double logscale = 0.0;

    auto step = [&](int t, float pv) {
        const float ef = (lane < CC) ? __expf(pv) : 0.0f;
        // gather emissions for this lane's 7 states (fp32, then widen)
        const double e0 = (double)bperm(cad[0], ef);
        const double e1 = (double)bperm(cad[1], ef);
        const double e2 = (double)bperm(cad[2], ef);
        const double e3 = (double)bperm(cad[3], ef);
        const double e4 = (double)bperm(cad[4], ef);
        const double e5 = (double)bperm(cad[5], ef);
        const double e6 = (double)bperm(cad[6], ef);
        // neighbor states from lane-1 (old values)
        const double pl1 = __shfl_up(a6, 1, 64) * lane0m;   // state 7l-1
        const double pl2 = __shfl_up(a5, 1, 64) * lane0m;   // state 7l-2
        const double n0 = (a0 + fma(skf[0], pl2, pl1)) * e0;
        const double n1 = (a1 + fma(skf[1], pl1, a0)) * e1;
        const double n2 = (a2 + fma(skf[2], a0, a1)) * e2;
        const double n3 = (a3 + fma(skf[3], a1, a2)) * e3;
        const double n4 = (a4 + fma(skf[4], a2, a3)) * e4;
        const double n5 = (a5 + fma(skf[5], a3, a4)) * e5;
        const double n6 = (a6 + fma(skf[6], a4, a5)) * e6;
        if (t < len) { a0 = n0; a1 = n1; a2 = n2; a3 = n3; a4 = n4; a5 = n5; a6 = n6; }
    };

    auto rescale = [&]() {
        double m = fmax(fmax(fmax(a0, a1), fmax(a2, a3)),
                        fmax(fmax(a4, a5), a6));
        #pragma unroll
        for (int o = 32; o > 0; o >>= 1) m = fmax(m, __shfl_xor(m, o, 64));
        if (m > 0.0) {
            const double inv = 1.0 / m;
            a0 *= inv; a1 *= inv; a2 *= inv; a3 *= inv;
            a4 *= inv; a5 *= inv; a6 *= inv;
            logscale += (double)__logf((float)m);
        }
    };

    // main loop: t = 1 .. 1992 in blocks of 8; tail t = 1993 .. 1999
    for (int it = 0; it < 249; ++it) {
        const int t  = 1 + it * 8;
        const int tb = t + 8;
        const float* pf = lprow + (size_t)tb * rowstride;
        const float q0 = (tb + 0 < TT) ? pf[0 * rowstride] : 0.0f;
        const float q1 = (tb + 1 < TT) ? pf[1 * rowstride] : 0.0f;
        const float q2 = (tb + 2 < TT) ? pf[2 * rowstride] : 0.0f;
        const float q3 = (tb + 3 < TT) ? pf[3 * rowstride] : 0.0f;
        const float q4 = (tb + 4 < TT) ? pf[4 * rowstride] : 0.0f;
        const float q5 = (tb + 5 < TT) ? pf[5 * rowstride] : 0.0f;
        const float q6 = (tb + 6 < TT) ? pf[6 * rowstride] : 0.0f;
        const float q7 = (tb + 7 < TT) ? pf[7 * rowstride] : 0.0f;
        step(t + 0, P0); step(t + 1, P1); step(t + 2, P2); step(t + 3, P3);
        step(t + 4, P4); step(t + 5, P5); step(t + 6, P6); step(t + 7, P7);
        rescale();
        P0 = q0; P1 = q1; P2 = q2; P3 = q3;
        P4 = q4; P5 = q5; P6 = q6; P7 = q7;
    }
    step(1993, P0); step(1994, P1); step(1995, P2); step(1996, P3);
    step(1997, P4); step(1998, P5); step(1999, P6);

    // ---- readout: sum alpha at states 2*tl and 2*tl-1, then loss ----
    double contrib = 0.0;
    #pragma unroll
    for (int i = 0; i < 7; ++i) {
        const int s = 7 * lane + i;
        const double av = (i == 0) ? a0 : (i == 1) ? a1 : (i == 2) ? a2 :
                          (i == 3) ? a3 : (i == 4) ? a4 : (i == 5) ? a5 : a6;
        if (s == 2 * tl || s == 2 * tl - 1) contrib += av;
    }
    #pragma unroll
    for (int o = 32; o > 0; o >>= 1) contrib += __shfl_xor(contrib, o, 64);

    if (lane == 0) {
        double lb = 0.0;
        if (contrib > 0.0) lb = -(log(contrib) + logscale);
        if (lb > 1e29) lb = 0.0;             // zero_infinity
        ws[b] = (float)(lb / (double)tl);
    }
}

// ---------------------------------------------------------------------------
// Kernel 3: mean over batches -> final loss scalar.
// ---------------------------------------------------------------------------
__global__ void k3_reduce(const float* __restrict__ ws, float* __restrict__ loss_out)
{
    if (threadIdx.x == 0 && blockIdx.x == 0) {
        float sum = 0.0f;
        #pragma unroll
        for (int b = 0; b < BB; ++b) sum += ws[b];
        *loss_out = sum / (float)BB;
    }
}

extern "C" void kernel_launch(void* const* d_in, const int* in_sizes, int n_in,
                              void* d_out, int out_size, void* d_ws, size_t ws_size,
                              hipStream_t stream) {
    const float* hidden = (const float*)d_in[0];   // (B,T,H) fp32
    const float* W      = (const float*)d_in[1];   // (C,H)  fp32
    const float* bias   = (const float*)d_in[2];   // (C,)   fp32
    const int* targets  = (const int*)d_in[3];     // (B,L)
    const int* in_len   = (const int*)d_in[4];     // (B,)
    const int* tg_len   = (const int*)d_in[5];     // (B,)

    float* out      = (float*)d_out;                       // log_prob (T,B,C)
    float* loss_out = out + (size_t)TT * BB * CC;          // scalar at [2560000]
    float* ws       = (float*)d_ws;                        // 32 floats

    k1_logits_lsm<<<dim3((BB * TT) / 256), dim3(256), 0, stream>>>(hidden, W, bias, out);
    k2_ctc<<<dim3(BB), dim3(64), 0, stream>>>(out, targets, in_len, tg_len, ws);
    k3_reduce<<<dim3(1), dim3(64), 0, stream>>>(ws, loss_out);
}

// Round 4
// 395.022 us; speedup vs baseline: 3.4478x; 1.6503x over previous
//
#include <hip/hip_runtime.h>
#include <hip/hip_bf16.h>

// Problem constants (from reference setup_inputs):
//   B=32, T=2000, H=512, L=200, C=40 (39 phones + blank=39)
// Outputs: log_prob (T,B,C) fp32 flat [0, 2560000) then loss scalar at [2560000].

#define BB 32
#define TT 2000
#define HH 512
#define CC 40
#define LL 200
#define NEGV -1e30f

typedef __attribute__((ext_vector_type(8))) short short8;
typedef __attribute__((ext_vector_type(4))) float f32x4;

__device__ __forceinline__ unsigned short f2bf(float f) {
    unsigned u = __float_as_uint(f);
    u = u + 0x7FFFu + ((u >> 16) & 1u);      // RNE truncate to bf16
    return (unsigned short)(u >> 16);
}

// lane i gets lane i-1's value; lane 0 gets 0. VALU DPP (wave_shr:1), no DS.
__device__ __forceinline__ double dshr1(double x) {
    int lo = __double2loint(x), hi = __double2hiint(x);
    lo = __builtin_amdgcn_update_dpp(0, lo, 0x138, 0xF, 0xF, false);
    hi = __builtin_amdgcn_update_dpp(0, hi, 0x138, 0xF, 0xF, false);
    return __hiloint2double(hi, lo);
}

// ---------------------------------------------------------------------------
// k0: convert W (C,H) fp32 -> padded bf16 (48,H), classes >= 40 zero.
// ---------------------------------------------------------------------------
__global__ void k0_wconv(const float* __restrict__ W, short* __restrict__ wbf) {
    const int idx = blockIdx.x * 256 + threadIdx.x;
    if (idx < 48 * HH) {
        const int n = idx >> 9, k = idx & (HH - 1);
        wbf[idx] = (n < CC) ? (short)f2bf(W[n * HH + k]) : (short)0;
    }
}

// ---------------------------------------------------------------------------
// k1 (fast): MFMA GEMM + log-softmax. One wave per 16 rows; N=48 (3 tiles),
// K=512 in 16 steps of 32. A: fp32 global -> bf16 in-register. B: bf16 from
// k0's buffer (cache-resident, 48 KB). No LDS, no barriers.
// C/D layout: col=lane&15, row=quad*4+reg. A: row=lane&15, k=quad*8+j.
// Also writes P = exp(log_prob) TRANSPOSED to (B,C,T) for k2's t-contiguous
// prefetch.
// ---------------------------------------------------------------------------
__global__ __launch_bounds__(256) void k1_mfma(
    const float* __restrict__ hidden,   // (B,T,H)
    const short* __restrict__ wbf,      // (48,H) bf16
    const float* __restrict__ bias,     // (C,)
    float* __restrict__ out,            // (T,B,C)
    float* __restrict__ P)              // (B,C,T) probs
{
    const int tid = threadIdx.x, lane = tid & 63, wv = tid >> 6;
    const int quad = lane >> 4, mcol = lane & 15;
    const int r0 = (blockIdx.x * 4 + wv) * 16;

    const float* aptr = hidden + (size_t)(r0 + mcol) * HH + quad * 8;
    const short* b0p = wbf + (0 * 16 + mcol) * HH + quad * 8;
    const short* b1p = wbf + (1 * 16 + mcol) * HH + quad * 8;
    const short* b2p = wbf + (2 * 16 + mcol) * HH + quad * 8;

    f32x4 acc0 = {0.f, 0.f, 0.f, 0.f};
    f32x4 acc1 = {0.f, 0.f, 0.f, 0.f};
    f32x4 acc2 = {0.f, 0.f, 0.f, 0.f};

    #pragma unroll 2
    for (int kc = 0; kc < 16; ++kc) {
        const float4 al = *(const float4*)(aptr + kc * 32);
        const float4 ah = *(const float4*)(aptr + kc * 32 + 4);
        short8 af;
        af[0] = f2bf(al.x); af[1] = f2bf(al.y); af[2] = f2bf(al.z); af[3] = f2bf(al.w);
        af[4] = f2bf(ah.x); af[5] = f2bf(ah.y); af[6] = f2bf(ah.z); af[7] = f2bf(ah.w);
        const short8 bf0 = *(const short8*)(b0p + kc * 32);
        const short8 bf1 = *(const short8*)(b1p + kc * 32);
        const short8 bf2 = *(const short8*)(b2p + kc * 32);
        acc0 = __builtin_amdgcn_mfma_f32_16x16x32_bf16(af, bf0, acc0, 0, 0, 0);
        acc1 = __builtin_amdgcn_mfma_f32_16x16x32_bf16(af, bf1, acc1, 0, 0, 0);
        acc2 = __builtin_amdgcn_mfma_f32_16x16x32_bf16(af, bf2, acc2, 0, 0, 0);
    }

    // epilogue: bias, row-wise log-softmax over 40 cols (cols 40-47 masked)
    const float bz0 = bias[mcol];
    const float bz1 = bias[16 + mcol];
    const float bz2 = (mcol < 8) ? bias[32 + mcol] : 0.0f;
    float L0[4], L1[4], L2[4], lse[4];
    #pragma unroll
    for (int j = 0; j < 4; ++j) {
        L0[j] = acc0[j] + bz0;
        L1[j] = acc1[j] + bz1;
        L2[j] = (mcol < 8) ? (acc2[j] + bz2) : NEGV;
    }
    #pragma unroll
    for (int j = 0; j < 4; ++j) {
        float m = fmaxf(fmaxf(L0[j], L1[j]), L2[j]);
        #pragma unroll
        for (int o = 1; o < 16; o <<= 1) m = fmaxf(m, __shfl_xor(m, o, 64));
        float s = __expf(L0[j] - m) + __expf(L1[j] - m)
                + ((mcol < 8) ? __expf(L2[j] - m) : 0.0f);
        #pragma unroll
        for (int o = 1; o < 16; o <<= 1) s += __shfl_xor(s, o, 64);
        lse[j] = m + __logf(s);
    }
    #pragma unroll
    for (int j = 0; j < 4; ++j) {
        const int r = r0 + quad * 4 + j;
        const int b = r / TT, t = r - b * TT;
        float* op = out + ((size_t)t * BB + b) * CC;
        float* pp = P + (size_t)b * CC * TT + t;
        const float v0 = L0[j] - lse[j];
        const float v1 = L1[j] - lse[j];
        op[mcol]      = v0;  pp[(size_t)mcol * TT]        = __expf(v0);
        op[16 + mcol] = v1;  pp[(size_t)(16 + mcol) * TT] = __expf(v1);
        if (mcol < 8) {
            const float v2 = L2[j] - lse[j];
            op[32 + mcol] = v2;  pp[(size_t)(32 + mcol) * TT] = __expf(v2);
        }
    }
}

// ---------------------------------------------------------------------------
// k2 (fast): CTC alpha recurrence, one wave per batch, 8 states/lane
// (s = 8*lane + i; even i = blank). FP64 linear domain. Per step: 20 f64 ops,
// ONE dpp wave-shift (prev lane's a7), ZERO DS/exp/bperm — emissions come
// pre-exp'd from the (B,C,T) P matrix via t-contiguous float4 prefetch
// (addresses t-invariant per lane). Rescale every 32 steps (f64 range: worst
// drift -12 nats/step * 32 = -384 >> -709 floor).
// ---------------------------------------------------------------------------
__global__ __launch_bounds__(64) void k2_fast(
    const float* __restrict__ P,             // (B,C,T) probs
    const int* __restrict__ targets,         // (B,L)
    const int* __restrict__ input_lengths,   // (B,)
    const int* __restrict__ target_lengths,  // (B,)
    float* __restrict__ loss_ws)             // (B,)
{
    const int b = blockIdx.x, l = threadIdx.x;
    const int len = input_lengths[b];
    const int tl  = target_lengths[b];
    const int S   = 2 * tl + 1;
    (void)S;

    // odd states of this lane: s = 8l + 2j+1 -> label index 4l + j
    int cls[4]; double sk[4];
    #pragma unroll
    for (int j = 0; j < 4; ++j) {
        const int idx = 4 * l + j;
        int c = CC - 1; double skv = 0.0;
        if (idx < tl) {
            c = targets[b * LL + idx];
            if (idx == 0) skv = 1.0;   // s==1: a[s-2] is 0; skip=true in ref
            else skv = (c != targets[b * LL + idx - 1]) ? 1.0 : 0.0;
        }
        cls[j] = c; sk[j] = skv;
    }

    const float* pj[5];
    #pragma unroll
    for (int j = 0; j < 4; ++j) pj[j] = P + (size_t)(b * CC + cls[j]) * TT;
    pj[4] = P + (size_t)(b * CC + (CC - 1)) * TT;   // blank row

    // t = 0 init
    double a0, a1, a2, a3, a4, a5, a6, a7;
    {
        const float pb0 = pj[4][0];
        const float pl0 = pj[0][0];
        a0 = (l == 0) ? (double)pb0 : 0.0;
        a1 = (l == 0) ? (double)pl0 : 0.0;
        a2 = a3 = a4 = a5 = a6 = a7 = 0.0;
    }

    float g0[5][8], g1[5][8];
    auto prefetch = [&](float (&g)[5][8]) {     // loads next 8 t's per row
        #pragma unroll
        for (int j = 0; j < 5; ++j) {
            const float4 lo = *(const float4*)(pj[j]);
            const float4 hi = *(const float4*)(pj[j] + 4);
            g[j][0] = lo.x; g[j][1] = lo.y; g[j][2] = lo.z; g[j][3] = lo.w;
            g[j][4] = hi.x; g[j][5] = hi.y; g[j][6] = hi.z; g[j][7] = hi.w;
            pj[j] += 8;
        }
    };
    prefetch(g0);                                // t = 0..7 (slot 0 unused)

    double logscale = 0.0;

    auto step = [&](int t, float e1f, float e3f, float e5f, float e7f, float bef) {
        const double be = (double)bef;
        const double p7 = dshr1(a7);             // prev lane's state 8l-1
        const double n0 = (a0 + p7) * be;
        const double n1 = (a1 + fma(sk[0], p7, a0)) * (double)e1f;
        const double n2 = (a2 + a1) * be;
        const double n3 = (a3 + fma(sk[1], a1, a2)) * (double)e3f;
        const double n4 = (a4 + a3) * be;
        const double n5 = (a5 + fma(sk[2], a3, a4)) * (double)e5f;
        const double n6 = (a6 + a5) * be;
        const double n7 = (a7 + fma(sk[3], a5, a6)) * (double)e7f;
        if (t < len) { a0 = n0; a1 = n1; a2 = n2; a3 = n3;
                       a4 = n4; a5 = n5; a6 = n6; a7 = n7; }
    };
    auto run8 = [&](const float (&g)[5][8], int tbase, int ufirst) {
        #pragma unroll
        for (int u = 0; u < 8; ++u)
            if (u >= ufirst)
                step(tbase + u, g[0][u], g[1][u], g[2][u], g[3][u], g[4][u]);
    };
    auto rescale = [&]() {
        double m = fmax(fmax(fmax(a0, a1), fmax(a2, a3)),
                        fmax(fmax(a4, a5), fmax(a6, a7)));
        #pragma unroll
        for (int o = 32; o > 0; o >>= 1) m = fmax(m, __shfl_xor(m, o, 64));
        if (m > 0.0) {
            const double inv = 1.0 / m;
            a0 *= inv; a1 *= inv; a2 *= inv; a3 *= inv;
            a4 *= inv; a5 *= inv; a6 *= inv; a7 *= inv;
            logscale += log(m);
        }
    };

    // 250 8-step blocks: block 0 = t 1..7, blocks 1..249 = 8 t's each.
    // Double-buffered g0/g1, rescale every 4 blocks (32 steps).
    for (int it = 0; it < 125; ++it) {
        const int t = 16 * it;
        prefetch(g1);                            // t+8 .. t+15
        run8(g0, t, (it == 0) ? 1 : 0);
        if (it < 124) prefetch(g0);              // t+16 .. t+23
        run8(g1, t + 8, 0);
        if (it & 1) rescale();
    }

    // readout: alpha at states 2*tl and 2*tl-1
    double contrib = 0.0;
    const int send = 2 * tl;
    #pragma unroll
    for (int i = 0; i < 8; ++i) {
        const int s = 8 * l + i;
        const double av = (i == 0) ? a0 : (i == 1) ? a1 : (i == 2) ? a2 :
                          (i == 3) ? a3 : (i == 4) ? a4 : (i == 5) ? a5 :
                          (i == 6) ? a6 : a7;
        if (s == send || s == send - 1) contrib += av;
    }
    #pragma unroll
    for (int o = 32; o > 0; o >>= 1) contrib += __shfl_xor(contrib, o, 64);

    if (l == 0) {
        double lb = 0.0;
        if (contrib > 0.0) lb = -(log(contrib) + logscale);
        if (lb > 1e29) lb = 0.0;                 // zero_infinity
        loss_ws[b] = (float)(lb / (double)tl);
    }
}

// ---------------------------------------------------------------------------
// k3: mean over batches -> final loss scalar.
// ---------------------------------------------------------------------------
__global__ void k3_reduce(const float* __restrict__ ws, float* __restrict__ loss_out)
{
    if (threadIdx.x == 0 && blockIdx.x == 0) {
        float sum = 0.0f;
        #pragma unroll
        for (int b = 0; b < BB; ++b) sum += ws[b];
        *loss_out = sum / (float)BB;
    }
}

// ===========================================================================
// FALLBACK path (round-3, proven): used only if ws_size too small for P.
// ===========================================================================
__global__ __launch_bounds__(256) void k1_lds(
    const float* __restrict__ hidden, const float* __restrict__ W,
    const float* __restrict__ bias, float* __restrict__ out)
{
    __shared__ float Wl[CC * 256];
    float4* Wl4 = (float4*)Wl;
    const int tid = threadIdx.x;
    const int r = blockIdx.x * blockDim.x + tid;
    const float4* __restrict__ h4 = (const float4*)(hidden + (size_t)r * HH);
    const float4* __restrict__ W4g = (const float4*)W;
    float acc[CC];
    #pragma unroll
    for (int c = 0; c < CC; ++c) acc[c] = 0.0f;
    for (int kc = 0; kc < 2; ++kc) {
        __syncthreads();
        #pragma unroll
        for (int i = 0; i < 10; ++i) {
            const int idx = tid + i * 256;
            const int c = idx >> 6, j4 = idx & 63;
            Wl4[idx] = W4g[c * 128 + kc * 64 + j4];
        }
        __syncthreads();
        #pragma unroll 2
        for (int k4 = 0; k4 < 64; ++k4) {
            const float4 h = h4[kc * 64 + k4];
            #pragma unroll
            for (int c = 0; c < CC; ++c) {
                const float4 w = Wl4[c * 64 + k4];
                acc[c] = fmaf(h.x, w.x, fmaf(h.y, w.y,
                         fmaf(h.z, w.z, fmaf(h.w, w.w, acc[c]))));
            }
        }
    }
    #pragma unroll
    for (int c = 0; c < CC; ++c) acc[c] += bias[c];
    float mx = acc[0];
    #pragma unroll
    for (int c = 1; c < CC; ++c) mx = fmaxf(mx, acc[c]);
    float s = 0.0f;
    #pragma unroll
    for (int c = 0; c < CC; ++c) s += __expf(acc[c] - mx);
    const float lse = mx + __logf(s);
    const int b = r / TT, t = r - b * TT;
    float4* __restrict__ o4 = (float4*)(out + ((size_t)t * BB + b) * CC);
    #pragma unroll
    for (int c4 = 0; c4 < CC / 4; ++c4) {
        float4 v;
        v.x = acc[4 * c4 + 0] - lse; v.y = acc[4 * c4 + 1] - lse;
        v.z = acc[4 * c4 + 2] - lse; v.w = acc[4 * c4 + 3] - lse;
        o4[c4] = v;
    }
}

__device__ __forceinline__ float bperm(int byteaddr, float v) {
    return __int_as_float(__builtin_amdgcn_ds_bpermute(byteaddr, __float_as_int(v)));
}

__global__ __launch_bounds__(64) void k2_legacy(
    const float* __restrict__ lp, const int* __restrict__ targets,
    const int* __restrict__ input_lengths, const int* __restrict__ target_lengths,
    float* __restrict__ ws)
{
    const int b = blockIdx.x, lane = threadIdx.x;
    const int len = input_lengths[b];
    const int tl = target_lengths[b];
    const int S = 2 * tl + 1;
    int cad[7]; double skf[7];
    #pragma unroll
    for (int i = 0; i < 7; ++i) {
        const int s = 7 * lane + i;
        int cls = 63; double sk = 0.0;
        if (s < S) {
            if (s & 1) {
                cls = targets[b * LL + (s >> 1)];
                if (s >= 3) sk = (cls != targets[b * LL + ((s - 3) >> 1)]) ? 1.0 : 0.0;
                else sk = 1.0;
            } else cls = CC - 1;
        }
        cad[i] = cls * 4; skf[i] = sk;
    }
    const double lane0m = (lane == 0) ? 0.0 : 1.0;
    const int lc = (lane < CC) ? lane : (CC - 1);
    const size_t rowstride = (size_t)BB * CC;
    const float* lprow = lp + (size_t)b * CC + lc;
    double a0, a1, a2, a3, a4, a5, a6;
    {
        const float v0 = lprow[0];
        const float e = (lane < CC) ? __expf(v0) : 0.0f;
        a0 = (lane == 0) ? (double)bperm(cad[0], e) : 0.0;
        a1 = (lane == 0) ? (double)bperm(cad[1], e) : 0.0;
        a2 = a3 = a4 = a5 = a6 = 0.0;
    }
    float Pr[8];
    #pragma unroll
    for (int u = 0; u < 8; ++u) Pr[u] = lprow[(size_t)(1 + u) * rowstride];
    double logscale = 0.0;
    auto step = [&](int t, float pv) {
        const float ef = (lane < CC) ? __expf(pv) : 0.0f;
        const double e0 = (double)bperm(cad[0], ef), e1 = (double)bperm(cad[1], ef);
        const double e2 = (double)bperm(cad[2], ef), e3 = (double)bperm(cad[3], ef);
        const double e4 = (double)bperm(cad[4], ef), e5 = (double)bperm(cad[5], ef);
        const double e6 = (double)bperm(cad[6], ef);
        const double pl1 = __shfl_up(a6, 1, 64) * lane0m;
        const double pl2 = __shfl_up(a5, 1, 64) * lane0m;
        const double n0 = (a0 + fma(skf[0], pl2, pl1)) * e0;
        const double n1 = (a1 + fma(skf[1], pl1, a0)) * e1;
        const double n2 = (a2 + fma(skf[2], a0, a1)) * e2;
        const double n3 = (a3 + fma(skf[3], a1, a2)) * e3;
        const double n4 = (a4 + fma(skf[4], a2, a3)) * e4;
        const double n5 = (a5 + fma(skf[5], a3, a4)) * e5;
        const double n6 = (a6 + fma(skf[6], a4, a5)) * e6;
        if (t < len) { a0 = n0; a1 = n1; a2 = n2; a3 = n3; a4 = n4; a5 = n5; a6 = n6; }
    };
    auto rescale = [&]() {
        double m = fmax(fmax(fmax(a0, a1), fmax(a2, a3)), fmax(fmax(a4, a5), a6));
        #pragma unroll
        for (int o = 32; o > 0; o >>= 1) m = fmax(m, __shfl_xor(m, o, 64));
        if (m > 0.0) {
            const double inv = 1.0 / m;
            a0 *= inv; a1 *= inv; a2 *= inv; a3 *= inv; a4 *= inv; a5 *= inv; a6 *= inv;
            logscale += (double)__logf((float)m);
        }
    };
    for (int it = 0; it < 249; ++it) {
        const int t = 1 + it * 8, tb = t + 8;
        const float* pf = lprow + (size_t)tb * rowstride;
        float q[8];
        #pragma unroll
        for (int u = 0; u < 8; ++u) q[u] = (tb + u < TT) ? pf[(size_t)u * rowstride] : 0.0f;
        #pragma unroll
        for (int u = 0; u < 8; ++u) step(t + u, Pr[u]);
        rescale();
        #pragma unroll
        for (int u = 0; u < 8; ++u) Pr[u] = q[u];
    }
    #pragma unroll
    for (int u = 0; u < 7; ++u) step(1993 + u, Pr[u]);
    double contrib = 0.0;
    #pragma unroll
    for (int i = 0; i < 7; ++i) {
        const int s = 7 * lane + i;
        const double av = (i == 0) ? a0 : (i == 1) ? a1 : (i == 2) ? a2 :
                          (i == 3) ? a3 : (i == 4) ? a4 : (i == 5) ? a5 : a6;
        if (s == 2 * tl || s == 2 * tl - 1) contrib += av;
    }
    #pragma unroll
    for (int o = 32; o > 0; o >>= 1) contrib += __shfl_xor(contrib, o, 64);
    if (lane == 0) {
        double lb = 0.0;
        if (contrib > 0.0) lb = -(log(contrib) + logscale);
        if (lb > 1e29) lb = 0.0;
        ws[b] = (float)(lb / (double)tl);
    }
}

extern "C" void kernel_launch(void* const* d_in, const int* in_sizes, int n_in,
                              void* d_out, int out_size, void* d_ws, size_t ws_size,
                              hipStream_t stream) {
    const float* hidden = (const float*)d_in[0];
    const float* W      = (const float*)d_in[1];
    const float* bias   = (const float*)d_in[2];
    const int* targets  = (const int*)d_in[3];
    const int* in_len   = (const int*)d_in[4];
    const int* tg_len   = (const int*)d_in[5];

    float* out      = (float*)d_out;
    float* loss_out = out + (size_t)TT * BB * CC;

    const size_t PELEMS   = (size_t)BB * CC * TT;                 // 2,560,000 floats
    const size_t WBF_OFF  = PELEMS;                                // float offset
    const size_t LOSS_OFF = PELEMS + (48 * HH * sizeof(short)) / sizeof(float);
    const size_t need     = (LOSS_OFF + BB) * sizeof(float);       // ~10.3 MB

    if (ws_size >= need) {
        float* P   = (float*)d_ws;                                 // (B,C,T)
        short* wbf = (short*)((float*)d_ws + WBF_OFF);             // (48,H) bf16
        float* lws = (float*)d_ws + LOSS_OFF;                      // (B,)
        k0_wconv<<<dim3(96), dim3(256), 0, stream>>>(W, wbf);
        k1_mfma<<<dim3(1000), dim3(256), 0, stream>>>(hidden, wbf, bias, out, P);
        k2_fast<<<dim3(BB), dim3(64), 0, stream>>>(P, targets, in_len, tg_len, lws);
        k3_reduce<<<dim3(1), dim3(64), 0, stream>>>(lws, loss_out);
    } else {
        float* lws = (float*)d_ws;
        k1_lds<<<dim3((BB * TT) / 256), dim3(256), 0, stream>>>(hidden, W, bias, out);
        k2_legacy<<<dim3(BB), dim3(64), 0, stream>>>(out, targets, in_len, tg_len, lws);
        k3_reduce<<<dim3(1), dim3(64), 0, stream>>>(lws, loss_out);
    }
}